// Round 1
// baseline (1295.459 us; speedup 1.0000x reference)
//
#include <hip/hip_runtime.h>
#include <hip/hip_bf16.h>
#include <stdint.h>

// WindowMSA fused kernel: per-window (49 tok, C=192, 6 heads x 32)
//   kv = x@Wqkv^T+b ; q = skip@Wskip^T+b, scaled ; attn = softmax(qk^T+bias+mask) ; out = (attn@v)@Wproj^T+b
// One block per window, 512 threads (8 waves), bf16 MFMA 16x16x32, M padded 49->64.

typedef __bf16 bf16;
typedef __attribute__((ext_vector_type(8))) __bf16 bf16x8;
typedef __attribute__((ext_vector_type(4))) float f32x4;

#define CDIM 192
#define NH 6
#define NTOK 49
#define QSCALE 0.17677669529663687f

// LDS byte offsets (dynamic shared blob)
#define OFF_X   0u        // [64][192] bf16, stride 384B, swizzled  (later reused as O)
#define OFF_S   24576u    // skip [64][192]
#define OFF_Q   49152u    // Q [64][192]
#define OFF_K   73728u    // K [64][192]
#define OFF_VT  98304u    // V^T [192][64] bf16, stride 128B, swizzled
#define OFF_P   122880u   // per-wave P strips: 8 x [16][64] bf16 (2048B each)
#define OFF_RPB 139264u   // rpb_table 169*6 f32
#define OFF_RPI 143328u   // rel_pos_index as u8, 2401
#define SMEM_BYTES 145792u

__device__ __forceinline__ uint32_t swz384(uint32_t row, uint32_t b) {
  return row * 384u + (b ^ ((row & 7u) << 4));
}
__device__ __forceinline__ uint32_t swz128(uint32_t row, uint32_t b) {
  return row * 128u + (b ^ ((row & 7u) << 4));
}
__device__ __forceinline__ uint16_t f2u(float f) { bf16 h = (bf16)f; return __builtin_bit_cast(uint16_t, h); }
__device__ __forceinline__ bf16x8 ldw8(const float* __restrict__ p) {
  float4 w0 = *(const float4*)p;
  float4 w1 = *(const float4*)(p + 4);
  bf16x8 b = {(bf16)w0.x, (bf16)w0.y, (bf16)w0.z, (bf16)w0.w,
              (bf16)w1.x, (bf16)w1.y, (bf16)w1.z, (bf16)w1.w};
  return b;
}

__global__ void __launch_bounds__(512)
wmsa_kernel(const float* __restrict__ x, const float* __restrict__ skip,
            const float* __restrict__ mask, const int* __restrict__ rpi,
            const float* __restrict__ rpb, const float* __restrict__ wqkv,
            const float* __restrict__ bqkv, const float* __restrict__ wskip,
            const float* __restrict__ bskip, const float* __restrict__ wproj,
            const float* __restrict__ bproj, float* __restrict__ out)
{
  extern __shared__ char smem[];
  const uint32_t tid  = threadIdx.x;
  const uint32_t lane = tid & 63u;
  const uint32_t wv   = tid >> 6;     // wave 0..7
  const uint32_t l15  = lane & 15u;
  const uint32_t lg   = lane >> 4;    // 0..3
  const uint32_t win  = blockIdx.x;

  // ---------------- Phase 0: stage inputs (f32 -> bf16, swizzled) ----------------
  {
    const float4* xw = (const float4*)(x    + (size_t)win * NTOK * CDIM);
    const float4* sw = (const float4*)(skip + (size_t)win * NTOK * CDIM);
    for (uint32_t i = tid; i < (NTOK * CDIM) / 4; i += 512) {     // 2352 float4, 48 per row
      uint32_t r = i / 48u, c4 = (i - r * 48u) * 4u;
      float4 a = xw[i], b = sw[i];
      *(uint2*)(smem + OFF_X + swz384(r, c4 * 2u)) =
          make_uint2(((uint32_t)f2u(a.y) << 16) | f2u(a.x), ((uint32_t)f2u(a.w) << 16) | f2u(a.z));
      *(uint2*)(smem + OFF_S + swz384(r, c4 * 2u)) =
          make_uint2(((uint32_t)f2u(b.y) << 16) | f2u(b.x), ((uint32_t)f2u(b.w) << 16) | f2u(b.z));
    }
    for (uint32_t i = tid; i < 15u * 48u; i += 512) {             // zero pad rows 49..63
      uint32_t r = 49u + i / 48u, c4 = (i % 48u) * 4u;
      *(uint2*)(smem + OFF_X + swz384(r, c4 * 2u)) = make_uint2(0u, 0u);
      *(uint2*)(smem + OFF_S + swz384(r, c4 * 2u)) = make_uint2(0u, 0u);
    }
    for (uint32_t i = tid; i < 169u * NH; i += 512) ((float*)(smem + OFF_RPB))[i] = rpb[i];
    for (uint32_t i = tid; i < NTOK * NTOK; i += 512) ((uint8_t*)(smem + OFF_RPI))[i] = (uint8_t)rpi[i];
  }
  __syncthreads();

  // ---------------- Phase 1: Q = skip@Wskip^T (+b)*scale ; KV = x@Wqkv^T (+b) ----
  // Q: 4 mt x 12 nt = 48 tiles, 6 per wave
  for (uint32_t tile = wv; tile < 48u; tile += 8u) {
    uint32_t mt = tile / 12u, nt = tile - mt * 12u;
    f32x4 acc = {0.f, 0.f, 0.f, 0.f};
    uint32_t orow = nt * 16u + l15;                    // output channel 0..191
    const float* wrow = wskip + (size_t)orow * CDIM + lg * 8u;
    #pragma unroll
    for (uint32_t kk = 0; kk < 6u; ++kk) {
      bf16x8 a = *(const bf16x8*)(smem + OFF_S + swz384(mt * 16u + l15, kk * 64u + lg * 16u));
      bf16x8 b = ldw8(wrow + kk * 32u);
      acc = __builtin_amdgcn_mfma_f32_16x16x32_bf16(a, b, acc, 0, 0, 0);
    }
    float bias = bskip[orow];
    #pragma unroll
    for (uint32_t r = 0; r < 4u; ++r) {
      uint32_t row = mt * 16u + lg * 4u + r;
      *(bf16*)(smem + OFF_Q + swz384(row, orow * 2u)) = (bf16)((acc[r] + bias) * QSCALE);
    }
  }
  // KV: 4 mt x 24 nt = 96 tiles, 12 per wave. cols 0..191 -> K, 192..383 -> V (transposed store)
  for (uint32_t tile = wv; tile < 96u; tile += 8u) {
    uint32_t mt = tile / 24u, nt = tile - mt * 24u;
    f32x4 acc = {0.f, 0.f, 0.f, 0.f};
    uint32_t orow = nt * 16u + l15;                    // 0..383
    const float* wrow = wqkv + (size_t)orow * CDIM + lg * 8u;
    #pragma unroll
    for (uint32_t kk = 0; kk < 6u; ++kk) {
      bf16x8 a = *(const bf16x8*)(smem + OFF_X + swz384(mt * 16u + l15, kk * 64u + lg * 16u));
      bf16x8 b = ldw8(wrow + kk * 32u);
      acc = __builtin_amdgcn_mfma_f32_16x16x32_bf16(a, b, acc, 0, 0, 0);
    }
    float bias = bqkv[orow];
    if (orow < CDIM) {
      #pragma unroll
      for (uint32_t r = 0; r < 4u; ++r) {
        uint32_t row = mt * 16u + lg * 4u + r;
        *(bf16*)(smem + OFF_K + swz384(row, orow * 2u)) = (bf16)(acc[r] + bias);
      }
    } else {
      uint32_t vo = orow - CDIM;                       // V channel 0..191
      uint32_t t0 = mt * 16u + lg * 4u;                // 4 consecutive tokens
      uint32_t lo = ((uint32_t)f2u(acc[1] + bias) << 16) | f2u(acc[0] + bias);
      uint32_t hi = ((uint32_t)f2u(acc[3] + bias) << 16) | f2u(acc[2] + bias);
      *(uint2*)(smem + OFF_VT + swz128(vo, t0 * 2u)) = make_uint2(lo, hi);
    }
  }
  __syncthreads();

  // ---------------- Phase 2: attention. wave -> strip (wv&3), heads 3*(wv>>2).. ----
  {
    const uint32_t st = wv & 3u;
    const uint32_t h0 = (wv >> 2) * 3u;
    char* sPw = smem + OFF_P + wv * 2048u;             // private [16][64] bf16 strip
    const float* mrow = mask + (size_t)(win & 63u) * NTOK * NTOK;
    const uint8_t* rpiT = (const uint8_t*)(smem + OFF_RPI);
    const float*   rpbT = (const float*)(smem + OFF_RPB);

    for (uint32_t h = h0; h < h0 + 3u; ++h) {
      // S = Q K^T : 4 n-tiles, K=32 (one MFMA each)
      bf16x8 qa = *(const bf16x8*)(smem + OFF_Q + swz384(st * 16u + l15, h * 64u + lg * 16u));
      f32x4 s[4];
      #pragma unroll
      for (uint32_t nt = 0; nt < 4u; ++nt) {
        bf16x8 kb = *(const bf16x8*)(smem + OFF_K + swz384(nt * 16u + l15, h * 64u + lg * 16u));
        f32x4 z = {0.f, 0.f, 0.f, 0.f};
        s[nt] = __builtin_amdgcn_mfma_f32_16x16x32_bf16(qa, kb, z, 0, 0, 0);
      }
      // bias + mask + key-pad masking
      #pragma unroll
      for (uint32_t nt = 0; nt < 4u; ++nt) {
        uint32_t j = nt * 16u + l15;
        #pragma unroll
        for (uint32_t r = 0; r < 4u; ++r) {
          uint32_t i = st * 16u + lg * 4u + r;
          float v = s[nt][r];
          if (j < NTOK) {
            if (i < NTOK) {
              uint32_t idx = rpiT[i * NTOK + j];
              v += rpbT[idx * NH + h] + mrow[i * NTOK + j];
            }
          } else v = -1e30f;
          s[nt][r] = v;
        }
      }
      // row softmax (row lives on the 16 lanes of group lg, regs r)
      #pragma unroll
      for (uint32_t r = 0; r < 4u; ++r) {
        float mm = fmaxf(fmaxf(s[0][r], s[1][r]), fmaxf(s[2][r], s[3][r]));
        mm = fmaxf(mm, __shfl_xor(mm, 1)); mm = fmaxf(mm, __shfl_xor(mm, 2));
        mm = fmaxf(mm, __shfl_xor(mm, 4)); mm = fmaxf(mm, __shfl_xor(mm, 8));
        float ss = 0.f;
        #pragma unroll
        for (uint32_t nt = 0; nt < 4u; ++nt) { float p = __expf(s[nt][r] - mm); s[nt][r] = p; ss += p; }
        ss += __shfl_xor(ss, 1); ss += __shfl_xor(ss, 2);
        ss += __shfl_xor(ss, 4); ss += __shfl_xor(ss, 8);
        float inv = 1.f / ss;
        #pragma unroll
        for (uint32_t nt = 0; nt < 4u; ++nt) s[nt][r] *= inv;
      }
      // P (D-layout) -> LDS strip -> A-layout fragments (same wave, no barrier)
      #pragma unroll
      for (uint32_t nt = 0; nt < 4u; ++nt) {
        uint32_t colb = (nt * 16u + l15) * 2u;
        #pragma unroll
        for (uint32_t r = 0; r < 4u; ++r)
          *(bf16*)(sPw + swz128(lg * 4u + r, colb)) = (bf16)s[nt][r];
      }
      bf16x8 pa0 = *(const bf16x8*)(sPw + swz128(l15, lg * 16u));
      bf16x8 pa1 = *(const bf16x8*)(sPw + swz128(l15, lg * 16u + 64u));
      // O = P V : 2 n-tiles of 16 dims, K=64 (2 MFMAs)
      #pragma unroll
      for (uint32_t nt2 = 0; nt2 < 2u; ++nt2) {
        uint32_t vrow = h * 32u + nt2 * 16u + l15;
        bf16x8 vb0 = *(const bf16x8*)(smem + OFF_VT + swz128(vrow, lg * 16u));
        bf16x8 vb1 = *(const bf16x8*)(smem + OFF_VT + swz128(vrow, lg * 16u + 64u));
        f32x4 z = {0.f, 0.f, 0.f, 0.f};
        f32x4 o = __builtin_amdgcn_mfma_f32_16x16x32_bf16(pa0, vb0, z, 0, 0, 0);
        o = __builtin_amdgcn_mfma_f32_16x16x32_bf16(pa1, vb1, o, 0, 0, 0);
        #pragma unroll
        for (uint32_t r = 0; r < 4u; ++r) {
          uint32_t row = st * 16u + lg * 4u + r;
          *(bf16*)(smem + OFF_X + swz384(row, (h * 32u + nt2 * 16u + l15) * 2u)) = (bf16)o[r];
        }
      }
    }
  }
  __syncthreads();

  // ---------------- Phase 3: out = O@Wproj^T + b ----------------
  for (uint32_t tile = wv; tile < 48u; tile += 8u) {
    uint32_t mt = tile / 12u, nt = tile - mt * 12u;
    f32x4 acc = {0.f, 0.f, 0.f, 0.f};
    uint32_t orow = nt * 16u + l15;
    const float* wrow = wproj + (size_t)orow * CDIM + lg * 8u;
    #pragma unroll
    for (uint32_t kk = 0; kk < 6u; ++kk) {
      bf16x8 a = *(const bf16x8*)(smem + OFF_X + swz384(mt * 16u + l15, kk * 64u + lg * 16u));
      bf16x8 b = ldw8(wrow + kk * 32u);
      acc = __builtin_amdgcn_mfma_f32_16x16x32_bf16(a, b, acc, 0, 0, 0);
    }
    float bias = bproj[orow];
    #pragma unroll
    for (uint32_t r = 0; r < 4u; ++r) {
      uint32_t row = mt * 16u + lg * 4u + r;
      if (row < NTOK)
        out[(size_t)win * (NTOK * CDIM) + row * CDIM + orow] = acc[r] + bias;
    }
  }
}

extern "C" void kernel_launch(void* const* d_in, const int* in_sizes, int n_in,
                              void* d_out, int out_size, void* d_ws, size_t ws_size,
                              hipStream_t stream) {
  const float* x     = (const float*)d_in[0];
  const float* skip  = (const float*)d_in[1];
  const float* mask  = (const float*)d_in[2];
  const int*   rpi   = (const int*)  d_in[3];
  const float* rpb   = (const float*)d_in[4];
  const float* wqkv  = (const float*)d_in[5];
  const float* bqkv  = (const float*)d_in[6];
  const float* wskip = (const float*)d_in[7];
  const float* bskip = (const float*)d_in[8];
  const float* wproj = (const float*)d_in[9];
  const float* bproj = (const float*)d_in[10];

  int nwin = in_sizes[0] / (NTOK * CDIM);
  hipFuncSetAttribute((const void*)wmsa_kernel,
                      hipFuncAttributeMaxDynamicSharedMemorySize, (int)SMEM_BYTES);
  wmsa_kernel<<<nwin, 512, SMEM_BYTES, stream>>>(x, skip, mask, rpi, rpb, wqkv, bqkv,
                                                 wskip, bskip, wproj, bproj, (float*)d_out);
}

// Round 3
// 708.957 us; speedup vs baseline: 1.8273x; 1.8273x over previous
//
#include <hip/hip_runtime.h>
#include <hip/hip_bf16.h>
#include <stdint.h>

// WindowMSA fused kernel, round 3: round-2 design + strip-swizzle fix.
// One block = one window (49 tok, C=192, 6 heads x 32). 512 threads, 8 waves.
// LDS 80.2KB -> 2 blocks/CU. Weights pre-converted to bf16 in d_ws.
// Wave wv: grp=wv>>2 (head group: heads 3*grp..+3), st=wv&3 (query strip).
// BUGFIX vs r2: strip stride is 192B (not a multiple of 128), so the XOR
// swizzle must only flip bits 4-5 ((row&3)<<4); flipping bit 6 escaped the
// row for bytes>=128 and corrupted the third head of each group.

typedef __bf16 bf16;
typedef __attribute__((ext_vector_type(8))) __bf16 bf16x8;
typedef __attribute__((ext_vector_type(4))) float f32x4;

#define CDIM 192
#define NH 6
#define NTOK 49
#define QSCALE 0.17677669529663687f

// LDS layout (dynamic blob)
#define OFF_KO   0u        // K [64][192] bf16, stride 384B, swizzled; reused as O
#define OFF_VT   24576u    // V^T [192][64] bf16, stride 128B, swizzled
#define OFF_STR  49152u    // 8 x 3072B per-wave strips [16][96] bf16, stride 192B
#define OFF_RPB  73728u    // rpb_table 169*6 f32 (4056B, padded to 4064)
#define OFF_RPI  77792u    // rel_pos_index u8, 2401B
#define SMEM_BYTES 80256u

__device__ __forceinline__ uint32_t swz384(uint32_t row, uint32_t b) {
  return row * 384u + (b ^ ((row & 7u) << 4));
}
__device__ __forceinline__ uint32_t swz128(uint32_t row, uint32_t b) {
  return row * 128u + (b ^ ((row & 7u) << 4));
}
__device__ __forceinline__ uint32_t swzS(uint32_t row, uint32_t b) {
  return row * 192u + (b ^ ((row & 3u) << 4));   // bits 4-5 only: 192 = 3*64
}
__device__ __forceinline__ uint32_t f2u(float f) { bf16 h = (bf16)f; return (uint32_t)__builtin_bit_cast(uint16_t, h); }
__device__ __forceinline__ bf16x8 lda8(const float* p) {
  float4 w0 = *(const float4*)p;
  float4 w1 = *(const float4*)(p + 4);
  bf16x8 b = {(bf16)w0.x, (bf16)w0.y, (bf16)w0.z, (bf16)w0.w,
              (bf16)w1.x, (bf16)w1.y, (bf16)w1.z, (bf16)w1.w};
  return b;
}

// ---- weight f32 -> bf16 pre-convert (into d_ws) ----
// ws layout (bf16 elements): [0,73728) wqkv, [73728,110592) wskip, [110592,147456) wproj
__global__ void __launch_bounds__(256)
wcvt_kernel(const float* __restrict__ wqkv, const float* __restrict__ wskip,
            const float* __restrict__ wproj, bf16* __restrict__ ws) {
  uint32_t i = (blockIdx.x * 256u + threadIdx.x) * 4u;   // 147456/4 = 36864 threads
  float4 v;
  if (i < 73728u)       v = *(const float4*)(wqkv + i);
  else if (i < 110592u) v = *(const float4*)(wskip + (i - 73728u));
  else                  v = *(const float4*)(wproj + (i - 110592u));
  uint32_t lo = (f2u(v.y) << 16) | f2u(v.x);
  uint32_t hi = (f2u(v.w) << 16) | f2u(v.z);
  *(uint2*)(ws + i) = make_uint2(lo, hi);
}

__global__ void __launch_bounds__(512, 4)
wmsa_kernel(const float* __restrict__ x, const float* __restrict__ skip,
            const float* __restrict__ mask, const int* __restrict__ rpi,
            const float* __restrict__ rpb, const bf16* __restrict__ wbf,
            const float* __restrict__ bqkv, const float* __restrict__ bskip,
            const float* __restrict__ bproj, float* __restrict__ out)
{
  extern __shared__ char smem[];
  const uint32_t tid  = threadIdx.x;
  const uint32_t lane = tid & 63u;
  const uint32_t wv   = tid >> 6;
  const uint32_t l15  = lane & 15u;
  const uint32_t lg   = lane >> 4;
  const uint32_t grp  = wv >> 2;          // 0..1 -> heads 3*grp..+3, KV half
  const uint32_t st   = wv & 3u;          // query strip
  const uint32_t h0   = grp * 3u;
  const uint32_t win  = blockIdx.x;
  char* strip = smem + OFF_STR + wv * 3072u;

  const bf16* wqkv_bf  = wbf;
  const bf16* wskip_bf = wbf + 73728u;
  const bf16* wproj_bf = wbf + 110592u;

  // ---------------- Phase 0: stage tiny tables ----------------
  for (uint32_t i = tid; i < 169u * NH; i += 512u) ((float*)(smem + OFF_RPB))[i] = rpb[i];
  for (uint32_t i = tid; i < NTOK * NTOK; i += 512u) ((uint8_t*)(smem + OFF_RPI))[i] = (uint8_t)rpi[i];

  // ---------------- Phase 1a: Q tiles (this wave's own heads) ----------------
  uint32_t arow = st * 16u + l15; if (arow > 48u) arow = 48u;   // clamp pad rows
  const float* skipw = skip + (size_t)win * (NTOK * CDIM) + arow * CDIM + lg * 8u;
  const float* xw    = x    + (size_t)win * (NTOK * CDIM) + arow * CDIM + lg * 8u;

  {
    f32x4 qacc[6] = {};
    #pragma unroll
    for (uint32_t kk = 0; kk < 6u; ++kk) {
      bf16x8 a = lda8(skipw + kk * 32u);
      #pragma unroll
      for (uint32_t ntl = 0; ntl < 6u; ++ntl) {
        uint32_t orow = grp * 96u + ntl * 16u + l15;
        bf16x8 b = *(const bf16x8*)(wskip_bf + orow * CDIM + kk * 32u + lg * 8u);
        qacc[ntl] = __builtin_amdgcn_mfma_f32_16x16x32_bf16(a, b, qacc[ntl], 0, 0, 0);
      }
    }
    #pragma unroll
    for (uint32_t ntl = 0; ntl < 6u; ++ntl) {
      uint32_t orow = grp * 96u + ntl * 16u + l15;
      float bias = bskip[orow];
      #pragma unroll
      for (uint32_t r = 0; r < 4u; ++r)
        *(bf16*)(strip + swzS(lg * 4u + r, (ntl * 16u + l15) * 2u)) =
            (bf16)((qacc[ntl][r] + bias) * QSCALE);
    }
  }

  // ---------------- Phase 1b: KV tiles -> K LDS / V^T LDS ----------------
  {
    f32x4 kv[12] = {};
    #pragma unroll
    for (uint32_t kk = 0; kk < 6u; ++kk) {
      bf16x8 a = lda8(xw + kk * 32u);
      #pragma unroll
      for (uint32_t ntl = 0; ntl < 12u; ++ntl) {
        uint32_t orow = grp * 192u + ntl * 16u + l15;   // 0..191 K, 192..383 V
        bf16x8 b = *(const bf16x8*)(wqkv_bf + orow * CDIM + kk * 32u + lg * 8u);
        kv[ntl] = __builtin_amdgcn_mfma_f32_16x16x32_bf16(a, b, kv[ntl], 0, 0, 0);
      }
    }
    if (grp == 0u) {
      #pragma unroll
      for (uint32_t ntl = 0; ntl < 12u; ++ntl) {
        uint32_t ch = ntl * 16u + l15;
        float bias = bqkv[ch];
        #pragma unroll
        for (uint32_t r = 0; r < 4u; ++r)
          *(bf16*)(smem + OFF_KO + swz384(st * 16u + lg * 4u + r, ch * 2u)) =
              (bf16)(kv[ntl][r] + bias);
      }
    } else {
      uint32_t t0 = st * 16u + lg * 4u;
      #pragma unroll
      for (uint32_t ntl = 0; ntl < 12u; ++ntl) {
        uint32_t ch = ntl * 16u + l15;
        float bias = bqkv[CDIM + ch];
        float vv[4];
        #pragma unroll
        for (uint32_t r = 0; r < 4u; ++r)
          vv[r] = (t0 + r < NTOK) ? (kv[ntl][r] + bias) : 0.f;   // zero pad tokens
        uint32_t lo = (f2u(vv[1]) << 16) | f2u(vv[0]);
        uint32_t hi = (f2u(vv[3]) << 16) | f2u(vv[2]);
        *(uint2*)(smem + OFF_VT + swz128(ch, t0 * 2u)) = make_uint2(lo, hi);
      }
    }
  }

  // qa fragments from own strip (same-wave LDS write->read; no barrier needed)
  bf16x8 qa[3];
  #pragma unroll
  for (uint32_t hl = 0; hl < 3u; ++hl)
    qa[hl] = *(const bf16x8*)(strip + swzS(l15, hl * 64u + lg * 16u));

  __syncthreads();   // barrier 1: K, VT ready; tables ready

  // ---------------- Phase 2: attention (O kept in registers) ----------------
  f32x4 oacc[3][2];
  {
    const float* mrow = mask + (size_t)(win & 63u) * NTOK * NTOK;
    const uint8_t* rpiT = (const uint8_t*)(smem + OFF_RPI);
    const float*   rpbT = (const float*)(smem + OFF_RPB);

    #pragma unroll
    for (uint32_t hl = 0; hl < 3u; ++hl) {
      uint32_t h = h0 + hl;
      f32x4 s[4];
      #pragma unroll
      for (uint32_t nt = 0; nt < 4u; ++nt) {
        bf16x8 kb = *(const bf16x8*)(smem + OFF_KO + swz384(nt * 16u + l15, h * 64u + lg * 16u));
        f32x4 z = {};
        s[nt] = __builtin_amdgcn_mfma_f32_16x16x32_bf16(qa[hl], kb, z, 0, 0, 0);
      }
      #pragma unroll
      for (uint32_t nt = 0; nt < 4u; ++nt) {
        uint32_t j = nt * 16u + l15;
        #pragma unroll
        for (uint32_t r = 0; r < 4u; ++r) {
          uint32_t i = st * 16u + lg * 4u + r;
          float v = s[nt][r];
          if (j < NTOK) {
            if (i < NTOK) {
              uint32_t idx = rpiT[i * NTOK + j];
              v += rpbT[idx * NH + h] + mrow[i * NTOK + j];
            }
          } else v = -1e30f;
          s[nt][r] = v;
        }
      }
      #pragma unroll
      for (uint32_t r = 0; r < 4u; ++r) {
        float mm = fmaxf(fmaxf(s[0][r], s[1][r]), fmaxf(s[2][r], s[3][r]));
        mm = fmaxf(mm, __shfl_xor(mm, 1)); mm = fmaxf(mm, __shfl_xor(mm, 2));
        mm = fmaxf(mm, __shfl_xor(mm, 4)); mm = fmaxf(mm, __shfl_xor(mm, 8));
        float ss = 0.f;
        #pragma unroll
        for (uint32_t nt = 0; nt < 4u; ++nt) { float p = __expf(s[nt][r] - mm); s[nt][r] = p; ss += p; }
        ss += __shfl_xor(ss, 1); ss += __shfl_xor(ss, 2);
        ss += __shfl_xor(ss, 4); ss += __shfl_xor(ss, 8);
        float inv = 1.f / ss;
        #pragma unroll
        for (uint32_t nt = 0; nt < 4u; ++nt) s[nt][r] *= inv;
      }
      // P (D-layout) -> strip -> A-layout (same-wave); bytes 0..127 only
      #pragma unroll
      for (uint32_t nt = 0; nt < 4u; ++nt) {
        uint32_t colb = (nt * 16u + l15) * 2u;
        #pragma unroll
        for (uint32_t r = 0; r < 4u; ++r)
          *(bf16*)(strip + swzS(lg * 4u + r, colb)) = (bf16)s[nt][r];
      }
      bf16x8 pa0 = *(const bf16x8*)(strip + swzS(l15, lg * 16u));
      bf16x8 pa1 = *(const bf16x8*)(strip + swzS(l15, 64u + lg * 16u));
      #pragma unroll
      for (uint32_t nt2 = 0; nt2 < 2u; ++nt2) {
        uint32_t vrow = h * 32u + nt2 * 16u + l15;
        bf16x8 vb0 = *(const bf16x8*)(smem + OFF_VT + swz128(vrow, lg * 16u));
        bf16x8 vb1 = *(const bf16x8*)(smem + OFF_VT + swz128(vrow, lg * 16u + 64u));
        f32x4 z = {};
        f32x4 o = __builtin_amdgcn_mfma_f32_16x16x32_bf16(pa0, vb0, z, 0, 0, 0);
        oacc[hl][nt2] = __builtin_amdgcn_mfma_f32_16x16x32_bf16(pa1, vb1, o, 0, 0, 0);
      }
    }
  }

  __syncthreads();   // barrier 2: K/VT now dead -> O can take K's region

  #pragma unroll
  for (uint32_t hl = 0; hl < 3u; ++hl)
    #pragma unroll
    for (uint32_t nt2 = 0; nt2 < 2u; ++nt2) {
      uint32_t ch = (h0 + hl) * 32u + nt2 * 16u + l15;
      #pragma unroll
      for (uint32_t r = 0; r < 4u; ++r)
        *(bf16*)(smem + OFF_KO + swz384(st * 16u + lg * 4u + r, ch * 2u)) =
            (bf16)oacc[hl][nt2][r];
    }

  __syncthreads();   // barrier 3: O ready

  // ---------------- Phase 3: out = O @ Wproj^T + b ----------------
  for (uint32_t tile = wv; tile < 48u; tile += 8u) {
    uint32_t mt = tile / 12u, ntp = tile - mt * 12u;
    f32x4 acc = {};
    uint32_t orow = ntp * 16u + l15;
    #pragma unroll
    for (uint32_t kk = 0; kk < 6u; ++kk) {
      bf16x8 a = *(const bf16x8*)(smem + OFF_KO + swz384(mt * 16u + l15, kk * 64u + lg * 16u));
      bf16x8 b = *(const bf16x8*)(wproj_bf + orow * CDIM + kk * 32u + lg * 8u);
      acc = __builtin_amdgcn_mfma_f32_16x16x32_bf16(a, b, acc, 0, 0, 0);
    }
    float bias = bproj[orow];
    #pragma unroll
    for (uint32_t r = 0; r < 4u; ++r) {
      uint32_t row = mt * 16u + lg * 4u + r;
      if (row < NTOK)
        out[(size_t)win * (NTOK * CDIM) + row * CDIM + orow] = acc[r] + bias;
    }
  }
}

extern "C" void kernel_launch(void* const* d_in, const int* in_sizes, int n_in,
                              void* d_out, int out_size, void* d_ws, size_t ws_size,
                              hipStream_t stream) {
  const float* x     = (const float*)d_in[0];
  const float* skip  = (const float*)d_in[1];
  const float* mask  = (const float*)d_in[2];
  const int*   rpi   = (const int*)  d_in[3];
  const float* rpb   = (const float*)d_in[4];
  const float* wqkv  = (const float*)d_in[5];
  const float* bqkv  = (const float*)d_in[6];
  const float* wskip = (const float*)d_in[7];
  const float* bskip = (const float*)d_in[8];
  const float* wproj = (const float*)d_in[9];
  const float* bproj = (const float*)d_in[10];

  bf16* wbf = (bf16*)d_ws;                     // 294,912 B of scratch
  wcvt_kernel<<<144, 256, 0, stream>>>(wqkv, wskip, wproj, wbf);

  int nwin = in_sizes[0] / (NTOK * CDIM);
  hipFuncSetAttribute((const void*)wmsa_kernel,
                      hipFuncAttributeMaxDynamicSharedMemorySize, (int)SMEM_BYTES);
  wmsa_kernel<<<nwin, 512, SMEM_BYTES, stream>>>(x, skip, mask, rpi, rpb, wbf,
                                                 bqkv, bskip, bproj, (float*)d_out);
}

// Round 4
// 486.122 us; speedup vs baseline: 2.6649x; 1.4584x over previous
//
#include <hip/hip_runtime.h>
#include <hip/hip_bf16.h>
#include <stdint.h>

// WindowMSA, round 4: split pipeline with big-M GEMMs (weights LDS-resident)
// and a high-occupancy per-window attention kernel.
//   wcvt:    weights f32->bf16 into ws
//   biasprep: bias5d[w][h][i][j] = rpb[rpi[i][j]][h] + mask[w][i][j]  (3.7MB)
//   qgemm:   Q = (skip@Wskip^T + b)*scale        -> ws (bf16, [200704][192])
//   kvgemm:  K,V = x@Wqkv^T + b                  -> ws (bf16, row-major each)
//   attn:    per (window, head-group): softmax(QK^T+bias5d)V -> O over Q in-place
//   proj:    out = O@Wproj^T + b                 -> d_out (f32)

typedef __bf16 bf16;
typedef __attribute__((ext_vector_type(8))) __bf16 bf16x8;
typedef __attribute__((ext_vector_type(4))) float f32x4;

#define CDIM 192
#define NH 6
#define NTOK 49
#define QSCALE 0.17677669529663687f

// ws byte offsets
#define WSB_WQKV   0u          // 73728 bf16 elems (384x192)
#define WSE_WSKIP  73728u      // elem offset
#define WSE_WPROJ  110592u
#define WSB_BIAS5D 294912u     // 64*6*49*49 f32 = 3,687,936 B
#define WSB_QO     4194304u    // 200704*192 bf16 = 77,070,336 B (Q, overwritten by O)
#define WSB_K      81264640u
#define WSB_V      158334976u  // end: 235,405,312 B

__device__ __forceinline__ uint32_t swz384(uint32_t row, uint32_t b) {
  return row * 384u + (b ^ ((row & 7u) << 4));
}
__device__ __forceinline__ uint32_t swz128(uint32_t row, uint32_t b) {
  return row * 128u + (b ^ ((row & 7u) << 4));
}
__device__ __forceinline__ uint32_t f2u(float f) { bf16 h = (bf16)f; return (uint32_t)__builtin_bit_cast(uint16_t, h); }
__device__ __forceinline__ bf16x8 lda8(const float* p) {
  float4 w0 = *(const float4*)p;
  float4 w1 = *(const float4*)(p + 4);
  bf16x8 b = {(bf16)w0.x, (bf16)w0.y, (bf16)w0.z, (bf16)w0.w,
              (bf16)w1.x, (bf16)w1.y, (bf16)w1.z, (bf16)w1.w};
  return b;
}

// ---- weights f32 -> bf16 ----
__global__ void __launch_bounds__(256)
wcvt_kernel(const float* __restrict__ wqkv, const float* __restrict__ wskip,
            const float* __restrict__ wproj, bf16* __restrict__ ws) {
  uint32_t i = (blockIdx.x * 256u + threadIdx.x) * 4u;   // 147456 elems / 4
  float4 v;
  if (i < 73728u)       v = *(const float4*)(wqkv + i);
  else if (i < 110592u) v = *(const float4*)(wskip + (i - 73728u));
  else                  v = *(const float4*)(wproj + (i - 110592u));
  *(uint2*)(ws + i) = make_uint2((f2u(v.y) << 16) | f2u(v.x), (f2u(v.w) << 16) | f2u(v.z));
}

// ---- bias5d = rpb[rpi] + mask ----
__global__ void __launch_bounds__(256)
biasprep_kernel(const int* __restrict__ rpi, const float* __restrict__ rpb,
                const float* __restrict__ mask, float* __restrict__ b5) {
  uint32_t t = blockIdx.x * 256u + threadIdx.x;
  if (t >= 64u * NH * NTOK * NTOK) return;
  uint32_t w  = t / (NH * NTOK * NTOK);
  uint32_t h  = (t / (NTOK * NTOK)) % NH;
  uint32_t ij = t % (NTOK * NTOK);
  b5[t] = rpb[(uint32_t)rpi[ij] * NH + h] + mask[(size_t)w * (NTOK * NTOK) + ij];
}

// ---- stage a 192x192 bf16 weight matrix into swizzled LDS ----
__device__ __forceinline__ void stage_w(char* lds, const bf16* __restrict__ w, uint32_t tid, uint32_t nthr) {
  for (uint32_t u = tid; u < 4608u; u += nthr) {        // 16B units
    uint32_t row = u / 24u, c16 = u - row * 24u;
    uint4 v = *(const uint4*)(w + row * 192u + c16 * 8u);
    *(uint4*)(lds + row * 384u + ((c16 * 16u) ^ ((row & 7u) << 4))) = v;
  }
}

// ---- Q GEMM: qo = (skip @ wskip^T + b) * scale, bf16 ----
__global__ void __launch_bounds__(512, 4)
qgemm_kernel(const float* __restrict__ skip, const bf16* __restrict__ wskip_bf,
             const float* __restrict__ bskip, bf16* __restrict__ qo, uint32_t nrows) {
  extern __shared__ char lds[];
  const uint32_t tid = threadIdx.x, lane = tid & 63u, wv = tid >> 6;
  const uint32_t l15 = lane & 15u, lg = lane >> 4;
  stage_w(lds, wskip_bf, tid, 512u);
  __syncthreads();

  uint32_t base = blockIdx.x * 128u + wv * 16u;
  uint32_t arow = base + l15; if (arow >= nrows) arow = nrows - 1u;
  const float* ap = skip + (size_t)arow * CDIM + lg * 8u;
  bf16x8 af[6];
  #pragma unroll
  for (uint32_t kk = 0; kk < 6u; ++kk) af[kk] = lda8(ap + kk * 32u);

  f32x4 acc[12] = {};
  #pragma unroll
  for (uint32_t kk = 0; kk < 6u; ++kk)
    #pragma unroll
    for (uint32_t ntl = 0; ntl < 12u; ++ntl) {
      bf16x8 wb = *(const bf16x8*)(lds + swz384(ntl * 16u + l15, kk * 64u + lg * 16u));
      acc[ntl] = __builtin_amdgcn_mfma_f32_16x16x32_bf16(af[kk], wb, acc[ntl], 0, 0, 0);
    }
  #pragma unroll
  for (uint32_t ntl = 0; ntl < 12u; ++ntl) {
    uint32_t ch = ntl * 16u + l15;
    float bias = bskip[ch];
    #pragma unroll
    for (uint32_t r = 0; r < 4u; ++r) {
      uint32_t row = base + lg * 4u + r;
      if (row < nrows) qo[(size_t)row * CDIM + ch] = (bf16)((acc[ntl][r] + bias) * QSCALE);
    }
  }
}

// ---- KV GEMM: k,v = x @ wqkv^T + b, bf16 row-major each ----
__global__ void __launch_bounds__(512, 4)
kvgemm_kernel(const float* __restrict__ x, const bf16* __restrict__ wqkv_bf,
              const float* __restrict__ bqkv, bf16* __restrict__ kbf,
              bf16* __restrict__ vbf, uint32_t nrows) {
  extern __shared__ char lds[];
  const uint32_t tid = threadIdx.x, lane = tid & 63u, wv = tid >> 6;
  const uint32_t l15 = lane & 15u, lg = lane >> 4;

  uint32_t base = blockIdx.x * 128u + wv * 16u;
  uint32_t arow = base + l15; if (arow >= nrows) arow = nrows - 1u;
  const float* ap = x + (size_t)arow * CDIM + lg * 8u;
  bf16x8 af[6];
  #pragma unroll
  for (uint32_t kk = 0; kk < 6u; ++kk) af[kk] = lda8(ap + kk * 32u);

  #pragma unroll
  for (uint32_t h2 = 0; h2 < 2u; ++h2) {
    if (h2) __syncthreads();                       // all reads of prev W done
    stage_w(lds, wqkv_bf + h2 * 36864u, tid, 512u);
    __syncthreads();
    f32x4 acc[12] = {};
    #pragma unroll
    for (uint32_t kk = 0; kk < 6u; ++kk)
      #pragma unroll
      for (uint32_t ntl = 0; ntl < 12u; ++ntl) {
        bf16x8 wb = *(const bf16x8*)(lds + swz384(ntl * 16u + l15, kk * 64u + lg * 16u));
        acc[ntl] = __builtin_amdgcn_mfma_f32_16x16x32_bf16(af[kk], wb, acc[ntl], 0, 0, 0);
      }
    bf16* dst = h2 ? vbf : kbf;
    #pragma unroll
    for (uint32_t ntl = 0; ntl < 12u; ++ntl) {
      uint32_t ch = ntl * 16u + l15;
      float bias = bqkv[h2 * CDIM + ch];
      #pragma unroll
      for (uint32_t r = 0; r < 4u; ++r) {
        uint32_t row = base + lg * 4u + r;
        if (row < nrows) dst[(size_t)row * CDIM + ch] = (bf16)(acc[ntl][r] + bias);
      }
    }
  }
}

// ---- attention: block = (window, head-group of 3). O overwrites Q in ws. ----
// LDS: VT [96 ch][64 tok] bf16 swz128 (12288B) + 4 strips 2048B = 20480B
__global__ void __launch_bounds__(256, 8)
attn_kernel(bf16* __restrict__ qo, const bf16* __restrict__ kbf,
            const bf16* __restrict__ vbf, const float* __restrict__ bias5d) {
  extern __shared__ char lds[];
  const uint32_t tid = threadIdx.x, lane = tid & 63u, wv = tid >> 6;
  const uint32_t l15 = lane & 15u, lg = lane >> 4;
  const uint32_t win = blockIdx.x >> 1, grp = blockIdx.x & 1u;
  const uint32_t st = wv;
  char* strip = lds + 12288u + wv * 2048u;
  const size_t wrow0 = (size_t)win * NTOK;

  // stage V^T tile (this grp's 96 channels), zero the pad token columns
  for (uint32_t i = tid; i < 588u; i += 256u) {          // 49 tok x 12 ch8
    uint32_t tok = i / 12u, c8 = i - tok * 12u;
    bf16x8 v = *(const bf16x8*)(vbf + (wrow0 + tok) * CDIM + grp * 96u + c8 * 8u);
    #pragma unroll
    for (uint32_t j = 0; j < 8u; ++j)
      *(bf16*)(lds + swz128(c8 * 8u + j, tok * 2u)) = v[j];
  }
  for (uint32_t i = tid; i < 96u * 15u; i += 256u) {
    uint32_t row = i / 15u, tok = 49u + (i - row * 15u);
    *(bf16*)(lds + swz128(row, tok * 2u)) = (bf16)0.f;
  }

  // Q fragments (read before barrier; O written only by this wave to these rows)
  uint32_t qrow = st * 16u + l15; if (qrow > 48u) qrow = 48u;
  bf16x8 qa[3];
  #pragma unroll
  for (uint32_t hl = 0; hl < 3u; ++hl)
    qa[hl] = *(const bf16x8*)(qo + (wrow0 + qrow) * CDIM + grp * 96u + hl * 32u + lg * 8u);

  __syncthreads();

  #pragma unroll
  for (uint32_t hl = 0; hl < 3u; ++hl) {
    uint32_t h = grp * 3u + hl;
    const float* b5 = bias5d + ((size_t)(win & 63u) * NH + h) * (NTOK * NTOK);
    f32x4 s[4];
    #pragma unroll
    for (uint32_t nt = 0; nt < 4u; ++nt) {
      uint32_t krow = nt * 16u + l15; if (krow > 48u) krow = 48u;
      bf16x8 kb = *(const bf16x8*)(kbf + (wrow0 + krow) * CDIM + h * 32u + lg * 8u);
      f32x4 z = {};
      s[nt] = __builtin_amdgcn_mfma_f32_16x16x32_bf16(qa[hl], kb, z, 0, 0, 0);
    }
    #pragma unroll
    for (uint32_t nt = 0; nt < 4u; ++nt) {
      uint32_t j = nt * 16u + l15;
      #pragma unroll
      for (uint32_t r = 0; r < 4u; ++r) {
        uint32_t i = st * 16u + lg * 4u + r;
        float v = s[nt][r];
        if (j < NTOK) { if (i < NTOK) v += b5[i * NTOK + j]; }
        else v = -1e30f;
        s[nt][r] = v;
      }
    }
    #pragma unroll
    for (uint32_t r = 0; r < 4u; ++r) {
      float mm = fmaxf(fmaxf(s[0][r], s[1][r]), fmaxf(s[2][r], s[3][r]));
      mm = fmaxf(mm, __shfl_xor(mm, 1)); mm = fmaxf(mm, __shfl_xor(mm, 2));
      mm = fmaxf(mm, __shfl_xor(mm, 4)); mm = fmaxf(mm, __shfl_xor(mm, 8));
      float ss = 0.f;
      #pragma unroll
      for (uint32_t nt = 0; nt < 4u; ++nt) { float p = __expf(s[nt][r] - mm); s[nt][r] = p; ss += p; }
      ss += __shfl_xor(ss, 1); ss += __shfl_xor(ss, 2);
      ss += __shfl_xor(ss, 4); ss += __shfl_xor(ss, 8);
      float inv = 1.f / ss;
      #pragma unroll
      for (uint32_t nt = 0; nt < 4u; ++nt) s[nt][r] *= inv;
    }
    // P (D-layout) -> strip -> A-layout (same wave, no barrier)
    #pragma unroll
    for (uint32_t nt = 0; nt < 4u; ++nt) {
      uint32_t colb = (nt * 16u + l15) * 2u;
      #pragma unroll
      for (uint32_t r = 0; r < 4u; ++r)
        *(bf16*)(strip + swz128(lg * 4u + r, colb)) = (bf16)s[nt][r];
    }
    bf16x8 pa0 = *(const bf16x8*)(strip + swz128(l15, lg * 16u));
    bf16x8 pa1 = *(const bf16x8*)(strip + swz128(l15, 64u + lg * 16u));
    #pragma unroll
    for (uint32_t nt2 = 0; nt2 < 2u; ++nt2) {
      uint32_t vrow = hl * 32u + nt2 * 16u + l15;        // grp-local channel
      bf16x8 vb0 = *(const bf16x8*)(lds + swz128(vrow, lg * 16u));
      bf16x8 vb1 = *(const bf16x8*)(lds + swz128(vrow, lg * 16u + 64u));
      f32x4 z = {};
      f32x4 o = __builtin_amdgcn_mfma_f32_16x16x32_bf16(pa0, vb0, z, 0, 0, 0);
      o = __builtin_amdgcn_mfma_f32_16x16x32_bf16(pa1, vb1, o, 0, 0, 0);
      #pragma unroll
      for (uint32_t r = 0; r < 4u; ++r) {
        uint32_t orow = st * 16u + lg * 4u + r;
        if (orow < NTOK)
          qo[(wrow0 + orow) * CDIM + grp * 96u + hl * 32u + nt2 * 16u + l15] = (bf16)o[r];
      }
    }
  }
}

// ---- proj GEMM: out = O @ wproj^T + b, f32 ----
__global__ void __launch_bounds__(512, 4)
proj_kernel(const bf16* __restrict__ qo, const bf16* __restrict__ wproj_bf,
            const float* __restrict__ bproj, float* __restrict__ out, uint32_t nrows) {
  extern __shared__ char lds[];
  const uint32_t tid = threadIdx.x, lane = tid & 63u, wv = tid >> 6;
  const uint32_t l15 = lane & 15u, lg = lane >> 4;
  stage_w(lds, wproj_bf, tid, 512u);
  __syncthreads();

  uint32_t base = blockIdx.x * 128u + wv * 16u;
  uint32_t arow = base + l15; if (arow >= nrows) arow = nrows - 1u;
  const bf16* ap = qo + (size_t)arow * CDIM + lg * 8u;
  bf16x8 af[6];
  #pragma unroll
  for (uint32_t kk = 0; kk < 6u; ++kk) af[kk] = *(const bf16x8*)(ap + kk * 32u);

  f32x4 acc[12] = {};
  #pragma unroll
  for (uint32_t kk = 0; kk < 6u; ++kk)
    #pragma unroll
    for (uint32_t ntl = 0; ntl < 12u; ++ntl) {
      bf16x8 wb = *(const bf16x8*)(lds + swz384(ntl * 16u + l15, kk * 64u + lg * 16u));
      acc[ntl] = __builtin_amdgcn_mfma_f32_16x16x32_bf16(af[kk], wb, acc[ntl], 0, 0, 0);
    }
  #pragma unroll
  for (uint32_t ntl = 0; ntl < 12u; ++ntl) {
    uint32_t ch = ntl * 16u + l15;
    float bias = bproj[ch];
    #pragma unroll
    for (uint32_t r = 0; r < 4u; ++r) {
      uint32_t row = base + lg * 4u + r;
      if (row < nrows) out[(size_t)row * CDIM + ch] = acc[ntl][r] + bias;
    }
  }
}

extern "C" void kernel_launch(void* const* d_in, const int* in_sizes, int n_in,
                              void* d_out, int out_size, void* d_ws, size_t ws_size,
                              hipStream_t stream) {
  const float* x     = (const float*)d_in[0];
  const float* skip  = (const float*)d_in[1];
  const float* mask  = (const float*)d_in[2];
  const int*   rpi   = (const int*)  d_in[3];
  const float* rpb   = (const float*)d_in[4];
  const float* wqkv  = (const float*)d_in[5];
  const float* bqkv  = (const float*)d_in[6];
  const float* wskip = (const float*)d_in[7];
  const float* bskip = (const float*)d_in[8];
  const float* wproj = (const float*)d_in[9];
  const float* bproj = (const float*)d_in[10];

  char* ws = (char*)d_ws;
  bf16*  wbf    = (bf16*)(ws + WSB_WQKV);
  float* bias5d = (float*)(ws + WSB_BIAS5D);
  bf16*  qo     = (bf16*)(ws + WSB_QO);
  bf16*  kbf    = (bf16*)(ws + WSB_K);
  bf16*  vbf    = (bf16*)(ws + WSB_V);

  uint32_t nwin  = (uint32_t)(in_sizes[0] / (NTOK * CDIM));
  uint32_t nrows = nwin * NTOK;
  uint32_t ngb   = (nrows + 127u) / 128u;

  hipFuncSetAttribute((const void*)qgemm_kernel,  hipFuncAttributeMaxDynamicSharedMemorySize, 73728);
  hipFuncSetAttribute((const void*)kvgemm_kernel, hipFuncAttributeMaxDynamicSharedMemorySize, 73728);
  hipFuncSetAttribute((const void*)proj_kernel,   hipFuncAttributeMaxDynamicSharedMemorySize, 73728);

  wcvt_kernel<<<144, 256, 0, stream>>>(wqkv, wskip, wproj, wbf);
  biasprep_kernel<<<(64u * NH * NTOK * NTOK + 255u) / 256u, 256, 0, stream>>>(rpi, rpb, mask, bias5d);
  qgemm_kernel<<<ngb, 512, 73728, stream>>>(skip, wbf + WSE_WSKIP, bskip, qo, nrows);
  kvgemm_kernel<<<ngb, 512, 73728, stream>>>(x, wbf, bqkv, kbf, vbf, nrows);
  attn_kernel<<<nwin * 2u, 256, 20480, stream>>>(qo, kbf, vbf, bias5d);
  proj_kernel<<<ngb, 512, 73728, stream>>>(qo, wbf + WSE_WPROJ, bproj, (float*)d_out, nrows);
}